// Round 1
// baseline (1549.135 us; speedup 1.0000x reference)
//
#include <hip/hip_runtime.h>
#include <stdint.h>

#define HD 768
#define NHEADS 12
#define DHEAD 64
#define BATCH 8
#define TLEN 64
#define ILEN 197

typedef __attribute__((ext_vector_type(8))) short short8;
typedef __attribute__((ext_vector_type(4))) float f32x4;

__device__ __forceinline__ short f2bf(float x) {
    union { float f; uint32_t u; } v; v.f = x;
    uint32_t r = v.u + 0x7FFFu + ((v.u >> 16) & 1u);
    return (short)(r >> 16);
}
__device__ __forceinline__ float bf2f(short s) {
    union { uint32_t u; float f; } v; v.u = ((uint32_t)(unsigned short)s) << 16;
    return v.f;
}

// ---------------------------------------------------------------------------
// Prep: build transposed bf16 weights.
//   WTt (rows 0..767 = Wt^T, 768..1535 = Wq^T)  hi+lo split
//   WTi (rows: Wi^T, Wk^T, Wv^T)                hi+lo split
//   W1T hi only (gate MLP tolerates bf16)
// ---------------------------------------------------------------------------
__global__ void prep_weights(const float* __restrict__ Wq, const float* __restrict__ Wk,
                             const float* __restrict__ Wv, const float* __restrict__ Wt,
                             const float* __restrict__ Wi, const float* __restrict__ W1,
                             short* __restrict__ WTt_h, short* __restrict__ WTt_l,
                             short* __restrict__ WTi_h, short* __restrict__ WTi_l,
                             short* __restrict__ W1T_h) {
    int tid = blockIdx.x * blockDim.x + threadIdx.x;
    const int total = 4608 * HD;
    if (tid >= total) return;
    int r = tid / HD;
    int kk = tid - r * HD;
    if (r < 1536) {
        const float* src = (r < 768) ? Wt : Wq;
        int n = (r < 768) ? r : r - 768;
        float x = src[kk * HD + n];
        short h = f2bf(x);
        WTt_h[tid] = h;
        WTt_l[tid] = f2bf(x - bf2f(h));
    } else if (r < 3840) {
        int rr = r - 1536;
        int seg = rr / 768;
        int n = rr - seg * 768;
        const float* src = (seg == 0) ? Wi : (seg == 1) ? Wk : Wv;
        float x = src[kk * HD + n];
        short h = f2bf(x);
        WTi_h[rr * HD + kk] = h;
        WTi_l[rr * HD + kk] = f2bf(x - bf2f(h));
    } else {
        int rr = r - 3840;
        W1T_h[rr * HD + kk] = f2bf(W1[kk * HD + rr]);
    }
}

// ---------------------------------------------------------------------------
// Projection GEMM: out = X @ W + b, fp32 in/out, hi/lo bf16 split MFMA
// (3 MFMAs per tile -> ~2^-17 relative error, near-fp32).
// Grid: (ceil(M/64), Ntotal/64). 4 waves, each wave = 16 rows.
// Output columns map to up to 3 segments of 768 (separate buffers/biases).
// ---------------------------------------------------------------------------
__global__ __launch_bounds__(256) void proj_kernel(
    const float* __restrict__ X, int M,
    const short* __restrict__ WTh, const short* __restrict__ WTl,
    const float* __restrict__ bias0, const float* __restrict__ bias1,
    const float* __restrict__ bias2,
    float* __restrict__ out0, float* __restrict__ out1, float* __restrict__ out2)
{
    int tid = threadIdx.x;
    int l = tid & 63, w = tid >> 6;
    int lo = l & 15, grp = l >> 4;
    int i_base = blockIdx.x * 64 + w * 16;
    int arow = i_base + lo;
    bool aok = arow < M;
    int j0 = blockIdx.y * 64;

    f32x4 zero4 = {0.f, 0.f, 0.f, 0.f};
    f32x4 acc[4];
#pragma unroll
    for (int js = 0; js < 4; ++js) acc[js] = zero4;

    const float* xrow = X + (size_t)(aok ? arow : 0) * HD;

#pragma unroll
    for (int kc = 0; kc < 24; ++kc) {
        int kb = kc * 32 + grp * 8;
        float4 xa = make_float4(0.f, 0.f, 0.f, 0.f), xb = xa;
        if (aok) {
            xa = *(const float4*)(xrow + kb);
            xb = *(const float4*)(xrow + kb + 4);
        }
        float xs[8] = {xa.x, xa.y, xa.z, xa.w, xb.x, xb.y, xb.z, xb.w};
        short8 ah, al;
#pragma unroll
        for (int e = 0; e < 8; ++e) {
            short hh = f2bf(xs[e]);
            ah[e] = hh;
            al[e] = f2bf(xs[e] - bf2f(hh));
        }
#pragma unroll
        for (int js = 0; js < 4; ++js) {
            const short* bph = WTh + (size_t)(j0 + js * 16 + lo) * HD + kb;
            const short* bpl = WTl + (size_t)(j0 + js * 16 + lo) * HD + kb;
            short8 bh = *(const short8*)bph;
            short8 bl = *(const short8*)bpl;
            acc[js] = __builtin_amdgcn_mfma_f32_16x16x32_bf16(ah, bh, acc[js], 0, 0, 0);
            acc[js] = __builtin_amdgcn_mfma_f32_16x16x32_bf16(ah, bl, acc[js], 0, 0, 0);
            acc[js] = __builtin_amdgcn_mfma_f32_16x16x32_bf16(al, bh, acc[js], 0, 0, 0);
        }
    }
#pragma unroll
    for (int js = 0; js < 4; ++js) {
        int c = j0 + js * 16 + lo;
        int seg = (c >= 1536) ? 2 : (c >= 768 ? 1 : 0);
        int coff = c - seg * 768;
        const float* bp = (seg == 0) ? bias0 : (seg == 1) ? bias1 : bias2;
        float* op = (seg == 0) ? out0 : (seg == 1) ? out1 : out2;
        float bvv = bp[coff];
#pragma unroll
        for (int r = 0; r < 4; ++r) {
            int orow = i_base + grp * 4 + r;
            if (orow < M) op[(size_t)orow * HD + coff] = acc[js][r] + bvv;
        }
    }
}

// ---------------------------------------------------------------------------
// Gate MLP (the 119-GFLOP kernel), fused: for each (b,t, i-tile of 64)
//   A[i,k] = te[b,t,k] * ie[b,i,k]  (built on the fly, bf16, full-K in VGPRs)
//   hidden = relu(A @ W1 + b1) ; logit[i] = hidden @ W2 ; gate = sigmoid
// N is looped in-WG (12 tiles of 64) so the W2 reduction stays local.
// B frags read straight from L2-resident W1T (no LDS in main loop).
// ---------------------------------------------------------------------------
__global__ __launch_bounds__(256) void gate_kernel(
    const float* __restrict__ te, const float* __restrict__ ie,
    const short* __restrict__ W1T, const float* __restrict__ b1,
    const float* __restrict__ W2, const float* __restrict__ b2,
    float* __restrict__ gate)
{
    __shared__ float te_s[HD];
    int bx = blockIdx.x;
    int it = bx & 3;
    int t = (bx >> 2) & 63;
    int b = bx >> 8;
    int tid = threadIdx.x;
    if (tid < 192)
        ((float4*)te_s)[tid] = ((const float4*)(te + (size_t)(b * 64 + t) * HD))[tid];
    __syncthreads();

    int l = tid & 63, w = tid >> 6;
    int lo = l & 15, grp = l >> 4;
    int i_base = it * 64 + w * 16;
    if (i_base >= ILEN) return;   // no barriers after this point
    int arow = i_base + lo;
    bool aok = arow < ILEN;
    const float* ierow = ie + (size_t)(b * ILEN + (aok ? arow : 0)) * HD;

    short8 a[24];
#pragma unroll
    for (int kc = 0; kc < 24; ++kc) {
        int kb = kc * 32 + grp * 8;
        float4 xa = make_float4(0.f, 0.f, 0.f, 0.f), xb = xa;
        if (aok) {
            xa = *(const float4*)(ierow + kb);
            xb = *(const float4*)(ierow + kb + 4);
        }
        float4 ta = *(const float4*)(te_s + kb);
        float4 tb = *(const float4*)(te_s + kb + 4);
        a[kc][0] = f2bf(xa.x * ta.x);
        a[kc][1] = f2bf(xa.y * ta.y);
        a[kc][2] = f2bf(xa.z * ta.z);
        a[kc][3] = f2bf(xa.w * ta.w);
        a[kc][4] = f2bf(xb.x * tb.x);
        a[kc][5] = f2bf(xb.y * tb.y);
        a[kc][6] = f2bf(xb.z * tb.z);
        a[kc][7] = f2bf(xb.w * tb.w);
    }

    float plog[4] = {0.f, 0.f, 0.f, 0.f};
    f32x4 zero4 = {0.f, 0.f, 0.f, 0.f};

    for (int nt = 0; nt < 12; ++nt) {
        int j0 = nt * 64;
        f32x4 acc[4];
#pragma unroll
        for (int js = 0; js < 4; ++js) acc[js] = zero4;

#pragma unroll
        for (int js = 0; js < 4; ++js) {
            const short* bp = W1T + (size_t)(j0 + js * 16 + lo) * HD + grp * 8;
#pragma unroll
            for (int kc = 0; kc < 24; ++kc) {
                short8 bf = *(const short8*)(bp + kc * 32);
                acc[js] = __builtin_amdgcn_mfma_f32_16x16x32_bf16(a[kc], bf, acc[js], 0, 0, 0);
            }
        }
#pragma unroll
        for (int js = 0; js < 4; ++js) {
            int j = j0 + js * 16 + lo;
            float b1v = b1[j], w2v = W2[j];
#pragma unroll
            for (int r = 0; r < 4; ++r) {
                float hh = acc[js][r] + b1v;
                hh = hh > 0.f ? hh : 0.f;
                plog[r] += hh * w2v;
            }
        }
    }
    // reduce the 16 lanes (same grp) that hold partial sums of the same row
#pragma unroll
    for (int m = 1; m <= 8; m <<= 1) {
#pragma unroll
        for (int r = 0; r < 4; ++r) plog[r] += __shfl_xor(plog[r], m);
    }
    if (lo == 0) {
        float b2v = b2[0];
#pragma unroll
        for (int r = 0; r < 4; ++r) {
            int orow = i_base + grp * 4 + r;
            if (orow < ILEN)
                gate[(size_t)(b * 64 + t) * ILEN + orow] =
                    1.f / (1.f + expf(-(plog[r] + b2v)));
        }
    }
}

// ---------------------------------------------------------------------------
// Cross-attention, fp32 VALU (tiny: ~0.3 GF). One WG per (b,h).
// k staged in LDS [197][65] (pad breaks bank conflicts); v read from L2
// (coalesced per-i rows); per-row online: scores -> softmax -> *gate -> PV.
// ---------------------------------------------------------------------------
__global__ __launch_bounds__(256) void attn_kernel(
    const float* __restrict__ q, const float* __restrict__ k,
    const float* __restrict__ v, const float* __restrict__ gate,
    float* __restrict__ out)
{
    __shared__ float k_s[ILEN * 65];
    __shared__ float p_s[4][200];
    int h = blockIdx.x % NHEADS;
    int b = blockIdx.x / NHEADS;
    int tid = threadIdx.x;
    for (int idx = tid; idx < ILEN * DHEAD; idx += 256) {
        int i = idx >> 6, d = idx & 63;
        k_s[i * 65 + d] = k[(size_t)(b * ILEN + i) * HD + h * DHEAD + d];
    }
    __syncthreads();

    int l = tid & 63, w = tid >> 6;
    for (int tt = 0; tt < 16; ++tt) {
        int t = w * 16 + tt;
        float qv = q[(size_t)(b * 64 + t) * HD + h * DHEAD + l];
        float s0 = 0.f, s1 = 0.f, s2 = 0.f, s3 = 0.f;
        int i0 = l, i1 = 64 + l, i2 = 128 + l;
        int i3c = (192 + l < ILEN) ? 192 + l : 0;   // safe LDS index for invalid lanes
        for (int d = 0; d < 64; ++d) {
            float qd = __shfl(qv, d);
            s0 += qd * k_s[i0 * 65 + d];
            s1 += qd * k_s[i1 * 65 + d];
            s2 += qd * k_s[i2 * 65 + d];
            s3 += qd * k_s[i3c * 65 + d];
        }
        float sc[4] = {s0, s1, s2, s3};
        float m = -3.0e38f;
#pragma unroll
        for (int rep = 0; rep < 4; ++rep) {
            int i = rep * 64 + l;
            sc[rep] = (i < ILEN) ? sc[rep] * 0.125f : -3.0e38f;
            m = fmaxf(m, sc[rep]);
        }
        for (int mask = 32; mask >= 1; mask >>= 1) m = fmaxf(m, __shfl_xor(m, mask));
        float sum = 0.f;
#pragma unroll
        for (int rep = 0; rep < 4; ++rep) {
            float e = __expf(sc[rep] - m);
            sc[rep] = e;
            sum += e;
        }
        for (int mask = 32; mask >= 1; mask >>= 1) sum += __shfl_xor(sum, mask);
        float inv = 1.f / sum;
        const float* grow = gate + (size_t)(b * 64 + t) * ILEN;
#pragma unroll
        for (int rep = 0; rep < 4; ++rep) {
            int i = rep * 64 + l;
            if (i < 200) p_s[w][i] = (i < ILEN) ? sc[rep] * inv * grow[i] : 0.f;
        }
        // same wave writes & reads p_s -> no barrier needed
        float ctx = 0.f;
        const float* vbase = v + (size_t)(b * ILEN) * HD + h * DHEAD + l;
        for (int c = 0; c < 49; ++c) {
            float4 p4 = *(const float4*)&p_s[w][c * 4];
            ctx += p4.x * vbase[(size_t)(c * 4 + 0) * HD];
            ctx += p4.y * vbase[(size_t)(c * 4 + 1) * HD];
            ctx += p4.z * vbase[(size_t)(c * 4 + 2) * HD];
            ctx += p4.w * vbase[(size_t)(c * 4 + 3) * HD];
        }
        {
            float4 p4 = *(const float4*)&p_s[w][196];
            ctx += p4.x * vbase[(size_t)196 * HD];   // i=197..199 have p==0
        }
        out[(size_t)(b * 64 + t) * HD + h * DHEAD + l] = ctx;
    }
}

// ---------------------------------------------------------------------------
extern "C" void kernel_launch(void* const* d_in, const int* in_sizes, int n_in,
                              void* d_out, int out_size, void* d_ws, size_t ws_size,
                              hipStream_t stream)
{
    const float* text  = (const float*)d_in[0];
    const float* image = (const float*)d_in[1];
    const float* Wq = (const float*)d_in[2];
    const float* bq = (const float*)d_in[3];
    const float* Wk = (const float*)d_in[4];
    const float* bk = (const float*)d_in[5];
    const float* Wv = (const float*)d_in[6];
    const float* bv = (const float*)d_in[7];
    const float* Wt = (const float*)d_in[8];
    const float* bt = (const float*)d_in[9];
    const float* Wi = (const float*)d_in[10];
    const float* bi = (const float*)d_in[11];
    const float* W1 = (const float*)d_in[12];
    const float* b1 = (const float*)d_in[13];
    const float* W2 = (const float*)d_in[14];
    const float* b2 = (const float*)d_in[15];
    float* out = (float*)d_out;

    char* ws = (char*)d_ws;
    size_t off = 0;
    auto carve = [&](size_t bytes) -> void* {
        void* p = (void*)(ws + off);
        off += (bytes + 255) & ~(size_t)255;
        return p;
    };
    short* WTt_h = (short*)carve((size_t)1536 * 768 * 2);
    short* WTt_l = (short*)carve((size_t)1536 * 768 * 2);
    short* WTi_h = (short*)carve((size_t)2304 * 768 * 2);
    short* WTi_l = (short*)carve((size_t)2304 * 768 * 2);
    short* W1T_h = (short*)carve((size_t)768 * 768 * 2);
    float* te    = (float*)carve((size_t)512 * 768 * 4);
    float* qb    = (float*)carve((size_t)512 * 768 * 4);
    float* ieb   = (float*)carve((size_t)1576 * 768 * 4);
    float* kb    = (float*)carve((size_t)1576 * 768 * 4);
    float* vb    = (float*)carve((size_t)1576 * 768 * 4);
    float* gateb = (float*)carve((size_t)BATCH * TLEN * ILEN * 4);

    hipLaunchKernelGGL(prep_weights, dim3(13824), dim3(256), 0, stream,
                       Wq, Wk, Wv, Wt, Wi, W1, WTt_h, WTt_l, WTi_h, WTi_l, W1T_h);
    hipLaunchKernelGGL(proj_kernel, dim3(8, 24), dim3(256), 0, stream,
                       text, 512, WTt_h, WTt_l, bt, bq, (const float*)nullptr,
                       te, qb, (float*)nullptr);
    hipLaunchKernelGGL(proj_kernel, dim3(25, 36), dim3(256), 0, stream,
                       image, 1576, WTi_h, WTi_l, bi, bk, bv,
                       ieb, kb, vb);
    hipLaunchKernelGGL(gate_kernel, dim3(2048), dim3(256), 0, stream,
                       te, ieb, W1T_h, b1, W2, b2, gateb);
    hipLaunchKernelGGL(attn_kernel, dim3(BATCH * NHEADS), dim3(256), 0, stream,
                       qb, kb, vb, gateb, out);
}

// Round 2
// 510.223 us; speedup vs baseline: 3.0362x; 3.0362x over previous
//
#include <hip/hip_runtime.h>
#include <stdint.h>

#define HD 768
#define NHEADS 12
#define DHEAD 64
#define BATCH 8
#define TLEN 64
#define ILEN 197

typedef __attribute__((ext_vector_type(8))) short short8;
typedef __attribute__((ext_vector_type(4))) float f32x4;

__device__ __forceinline__ short f2bf(float x) {
    union { float f; uint32_t u; } v; v.f = x;
    uint32_t r = v.u + 0x7FFFu + ((v.u >> 16) & 1u);
    return (short)(r >> 16);
}
__device__ __forceinline__ float bf2f(short s) {
    union { uint32_t u; float f; } v; v.u = ((uint32_t)(unsigned short)s) << 16;
    return v.f;
}
__device__ __forceinline__ void gll16(const void* g, void* l) {
    __builtin_amdgcn_global_load_lds(
        (const __attribute__((address_space(1))) unsigned int*)g,
        (__attribute__((address_space(3))) unsigned int*)l, 16, 0, 0);
}

// ---------------------------------------------------------------------------
// Prep: LDS-tiled transpose of weights into swizzled bf16 chunk layouts.
// W5s: 5 mats (Wt,Wq,Wi,Wk,Wv), chunks of [64 col][64 k], planes h+l:
//   short idx within plane = (col*64 + kloc) ^ ((col&7)<<3)
//   chunk base (shorts) = ((seg*12 + ntile)*12 + kt)*8192, plane l at +4096
// W1Ts: chunks [64 col][128 k], h only:
//   chunk c = ntile*6 + kt/2; idx = (col*128 + klocal) ^ ((col&7)<<3)
// Linear global_load_lds of a chunk then reproduces the swizzled LDS image.
// ---------------------------------------------------------------------------
__global__ __launch_bounds__(256) void prep_weights(
    const float* __restrict__ Wq, const float* __restrict__ Wk,
    const float* __restrict__ Wv, const float* __restrict__ Wt,
    const float* __restrict__ Wi, const float* __restrict__ W1,
    short* __restrict__ W5s, short* __restrict__ W1Ts)
{
    __shared__ float tile[64][65];
    int bx = blockIdx.x;
    int tid = threadIdx.x;
    bool isW1 = bx >= 720;
    const float* src;
    int seg, ti;
    if (isW1) { src = W1; ti = bx - 720; seg = 5; }
    else {
        seg = bx / 144; ti = bx - seg * 144;
        src = (seg == 0) ? Wt : (seg == 1) ? Wq : (seg == 2) ? Wi : (seg == 3) ? Wk : Wv;
    }
    int kt = ti / 12, ntile = ti - kt * 12;
#pragma unroll
    for (int pass = 0; pass < 16; ++pass) {
        int idx = pass * 256 + tid;
        int kk = idx >> 6, nn = idx & 63;
        tile[kk][nn] = src[(size_t)(kt * 64 + kk) * HD + ntile * 64 + nn];
    }
    __syncthreads();
    if (!isW1) {
        size_t base = ((size_t)(seg * 12 + ntile) * 12 + kt) * 8192;
#pragma unroll
        for (int pass = 0; pass < 16; ++pass) {
            int idx = pass * 256 + tid;
            int col = idx >> 6, kloc = idx & 63;
            float x = tile[kloc][col];
            short h = f2bf(x);
            short lw = f2bf(x - bf2f(h));
            int sidx = (col * 64 + kloc) ^ ((col & 7) << 3);
            W5s[base + sidx] = h;
            W5s[base + 4096 + sidx] = lw;
        }
    } else {
        int c = ntile * 6 + (kt >> 1);
        size_t base = (size_t)c * 8192;
        int khalf = (kt & 1) * 64;
#pragma unroll
        for (int pass = 0; pass < 16; ++pass) {
            int idx = pass * 256 + tid;
            int col = idx >> 6, kloc = idx & 63;
            float x = tile[kloc][col];
            int klocal = khalf + kloc;
            int sidx = (col * 128 + klocal) ^ ((col & 7) << 3);
            W1Ts[base + sidx] = f2bf(x);
        }
    }
}

// ---------------------------------------------------------------------------
// Projection GEMM (hi/lo bf16 split, near-fp32). Block = 4 waves x 16 rows,
// one 64-col n-tile; K looped over 12 LDS-staged chunks (64k x {h,l}) with
// double buffer + counted vmcnt + raw barriers.
// ---------------------------------------------------------------------------
__global__ __launch_bounds__(256, 2) void proj_kernel(
    const float* __restrict__ X, int M,
    const short* __restrict__ W5s, int segbase,
    const float* __restrict__ bias0, const float* __restrict__ bias1,
    const float* __restrict__ bias2,
    float* __restrict__ out0, float* __restrict__ out1, float* __restrict__ out2)
{
    __shared__ __align__(16) short Bs[2][8192];
    int tid = threadIdx.x;
    int l = tid & 63, w = tid >> 6;
    int lo = l & 15, grp = l >> 4;
    int y = blockIdx.y;
    int segl = y / 12, ntile = y - segl * 12;
    int seg = segbase + segl;
    const char* wsrc = (const char*)W5s + (size_t)((seg * 12 + ntile) * 12) * 16384;
    {
        const char* s = wsrc + w * 4096 + l * 16;
        char* d = (char*)&Bs[0][0] + w * 4096;
        gll16(s, d); gll16(s + 1024, d + 1024);
        gll16(s + 2048, d + 2048); gll16(s + 3072, d + 3072);
    }
    int arow = blockIdx.x * 64 + w * 16 + lo;
    bool aok = arow < M;
    const float* xrow = X + (size_t)(aok ? arow : 0) * HD;
    short8 ah[24], al[24];
#pragma unroll
    for (int kc = 0; kc < 24; ++kc) {
        int kb = kc * 32 + grp * 8;
        float4 xa = {0.f, 0.f, 0.f, 0.f}, xb = {0.f, 0.f, 0.f, 0.f};
        if (aok) { xa = *(const float4*)(xrow + kb); xb = *(const float4*)(xrow + kb + 4); }
        float xs[8] = {xa.x, xa.y, xa.z, xa.w, xb.x, xb.y, xb.z, xb.w};
#pragma unroll
        for (int e = 0; e < 8; ++e) {
            short hh = f2bf(xs[e]);
            ah[kc][e] = hh;
            al[kc][e] = f2bf(xs[e] - bf2f(hh));
        }
    }
    __syncthreads();   // buf0 staged (drained) + all waves ready

    f32x4 acc[4];
    f32x4 z4 = {0.f, 0.f, 0.f, 0.f};
#pragma unroll
    for (int js = 0; js < 4; ++js) acc[js] = z4;

#pragma unroll
    for (int kk = 0; kk < 12; ++kk) {
        const short* buf = &Bs[kk & 1][0];
        if (kk < 11) {
            const char* s = wsrc + (size_t)(kk + 1) * 16384 + w * 4096 + l * 16;
            char* d = (char*)&Bs[(kk + 1) & 1][0] + w * 4096;
            gll16(s, d); gll16(s + 1024, d + 1024);
            gll16(s + 2048, d + 2048); gll16(s + 3072, d + 3072);
            asm volatile("s_waitcnt vmcnt(4)" ::: "memory");
        } else {
            asm volatile("s_waitcnt vmcnt(0)" ::: "memory");
        }
        __builtin_amdgcn_s_barrier();
        asm volatile("" ::: "memory");
#pragma unroll
        for (int js = 0; js < 4; ++js) {
            int col = js * 16 + lo;
            int base = col * 64;
            int sw = (col & 7) << 3;
#pragma unroll
            for (int kcl = 0; kcl < 2; ++kcl) {
                int idx = (base + kcl * 32 + grp * 8) ^ sw;
                short8 bh = *(const short8*)&buf[idx];
                short8 bl = *(const short8*)&buf[4096 + idx];
                int kc = kk * 2 + kcl;
                acc[js] = __builtin_amdgcn_mfma_f32_16x16x32_bf16(ah[kc], bh, acc[js], 0, 0, 0);
                acc[js] = __builtin_amdgcn_mfma_f32_16x16x32_bf16(ah[kc], bl, acc[js], 0, 0, 0);
                acc[js] = __builtin_amdgcn_mfma_f32_16x16x32_bf16(al[kc], bh, acc[js], 0, 0, 0);
            }
        }
        asm volatile("s_waitcnt lgkmcnt(0)" ::: "memory");
        __builtin_amdgcn_s_barrier();
        asm volatile("" ::: "memory");
    }
    const float* bp = (segl == 0) ? bias0 : (segl == 1) ? bias1 : bias2;
    float* op = (segl == 0) ? out0 : (segl == 1) ? out1 : out2;
#pragma unroll
    for (int js = 0; js < 4; ++js) {
        int cc = ntile * 64 + js * 16 + lo;
        float bvv = bp[cc];
#pragma unroll
        for (int r = 0; r < 4; ++r) {
            int orow = blockIdx.x * 64 + w * 16 + grp * 4 + r;
            if (orow < M) op[(size_t)orow * HD + cc] = acc[js][r] + bvv;
        }
    }
}

// ---------------------------------------------------------------------------
// Gate MLP: flattened pairs p = ((b*64+t)*197+i), 788 blocks x 128 rows
// (4 waves x 32 rows: 2 A-frags, full K=768 in 192 VGPRs). Loops 12 n-tiles
// x 6 K-chunks (64col x 128k, 16 KB) LDS double-buffered; epilogue fuses
// relu + W2 reduction; writes sigmoid(logit). No atomics, zero padding waste.
// ---------------------------------------------------------------------------
__global__ __launch_bounds__(256, 2) void gate_kernel(
    const float* __restrict__ te, const float* __restrict__ ie,
    const short* __restrict__ W1Ts, const float* __restrict__ b1,
    const float* __restrict__ W2, const float* __restrict__ b2,
    float* __restrict__ gate)
{
    __shared__ __align__(16) short Bs[2][8192];
    __shared__ float bw_s[1536];
    int tid = threadIdx.x;
    int l = tid & 63, w = tid >> 6;
    int lo = l & 15, grp = l >> 4;
    int pbase = blockIdx.x * 128 + w * 32;

    const char* wsrc = (const char*)W1Ts;
    {
        const char* s = wsrc + w * 4096 + l * 16;
        char* d = (char*)&Bs[0][0] + w * 4096;
        gll16(s, d); gll16(s + 1024, d + 1024);
        gll16(s + 2048, d + 2048); gll16(s + 3072, d + 3072);
    }
    for (int idx = tid; idx < 1536; idx += 256)
        bw_s[idx] = (idx < 768) ? b1[idx] : W2[idx - 768];

    short8 a0[24], a1[24];
    {
        int p0 = pbase + lo;
        int bb = p0 / 12608; int rr = p0 - bb * 12608;
        int t0 = rr / 197;   int i0 = rr - t0 * 197;
        const float* tp = te + (size_t)(bb * 64 + t0) * HD;
        const float* ip = ie + (size_t)(bb * 197 + i0) * HD;
#pragma unroll
        for (int kc = 0; kc < 24; ++kc) {
            int kb = kc * 32 + grp * 8;
            float4 xa = *(const float4*)(ip + kb);
            float4 xb = *(const float4*)(ip + kb + 4);
            float4 ta = *(const float4*)(tp + kb);
            float4 tb = *(const float4*)(tp + kb + 4);
            a0[kc][0] = f2bf(xa.x * ta.x); a0[kc][1] = f2bf(xa.y * ta.y);
            a0[kc][2] = f2bf(xa.z * ta.z); a0[kc][3] = f2bf(xa.w * ta.w);
            a0[kc][4] = f2bf(xb.x * tb.x); a0[kc][5] = f2bf(xb.y * tb.y);
            a0[kc][6] = f2bf(xb.z * tb.z); a0[kc][7] = f2bf(xb.w * tb.w);
        }
    }
    {
        int p1 = pbase + 16 + lo;
        int bb = p1 / 12608; int rr = p1 - bb * 12608;
        int t1 = rr / 197;   int i1 = rr - t1 * 197;
        const float* tp = te + (size_t)(bb * 64 + t1) * HD;
        const float* ip = ie + (size_t)(bb * 197 + i1) * HD;
#pragma unroll
        for (int kc = 0; kc < 24; ++kc) {
            int kb = kc * 32 + grp * 8;
            float4 xa = *(const float4*)(ip + kb);
            float4 xb = *(const float4*)(ip + kb + 4);
            float4 ta = *(const float4*)(tp + kb);
            float4 tb = *(const float4*)(tp + kb + 4);
            a1[kc][0] = f2bf(xa.x * ta.x); a1[kc][1] = f2bf(xa.y * ta.y);
            a1[kc][2] = f2bf(xa.z * ta.z); a1[kc][3] = f2bf(xa.w * ta.w);
            a1[kc][4] = f2bf(xb.x * tb.x); a1[kc][5] = f2bf(xb.y * tb.y);
            a1[kc][6] = f2bf(xb.z * tb.z); a1[kc][7] = f2bf(xb.w * tb.w);
        }
    }
    __syncthreads();   // buf0 ready, bw_s ready

    f32x4 z4 = {0.f, 0.f, 0.f, 0.f};
    f32x4 acc0[4], acc1[4];
#pragma unroll
    for (int js = 0; js < 4; ++js) { acc0[js] = z4; acc1[js] = z4; }
    float pl0[4] = {0.f, 0.f, 0.f, 0.f}, pl1[4] = {0.f, 0.f, 0.f, 0.f};

    for (int nt = 0; nt < 12; ++nt) {
#pragma unroll
        for (int kk = 0; kk < 6; ++kk) {
            int c = nt * 6 + kk;
            const short* buf = &Bs[kk & 1][0];
            if (c < 71) {
                const char* s = wsrc + (size_t)(c + 1) * 16384 + w * 4096 + l * 16;
                char* d = (char*)&Bs[(kk + 1) & 1][0] + w * 4096;
                gll16(s, d); gll16(s + 1024, d + 1024);
                gll16(s + 2048, d + 2048); gll16(s + 3072, d + 3072);
                asm volatile("s_waitcnt vmcnt(4)" ::: "memory");
            } else {
                asm volatile("s_waitcnt vmcnt(0)" ::: "memory");
            }
            __builtin_amdgcn_s_barrier();
            asm volatile("" ::: "memory");
#pragma unroll
            for (int js = 0; js < 4; ++js) {
                int col = js * 16 + lo;
                int base = col * 128;
                int sw = (col & 7) << 3;
#pragma unroll
                for (int kcl = 0; kcl < 4; ++kcl) {
                    int idx = (base + kcl * 32 + grp * 8) ^ sw;
                    short8 bf = *(const short8*)&buf[idx];
                    acc0[js] = __builtin_amdgcn_mfma_f32_16x16x32_bf16(a0[kk * 4 + kcl], bf, acc0[js], 0, 0, 0);
                    acc1[js] = __builtin_amdgcn_mfma_f32_16x16x32_bf16(a1[kk * 4 + kcl], bf, acc1[js], 0, 0, 0);
                }
            }
            if (kk == 5) {
#pragma unroll
                for (int js = 0; js < 4; ++js) {
                    int j = nt * 64 + js * 16 + lo;
                    float b1v = bw_s[j], w2v = bw_s[768 + j];
#pragma unroll
                    for (int r = 0; r < 4; ++r) {
                        pl0[r] += fmaxf(acc0[js][r] + b1v, 0.f) * w2v;
                        pl1[r] += fmaxf(acc1[js][r] + b1v, 0.f) * w2v;
                    }
                    acc0[js] = z4; acc1[js] = z4;
                }
            }
            asm volatile("s_waitcnt lgkmcnt(0)" ::: "memory");
            __builtin_amdgcn_s_barrier();
            asm volatile("" ::: "memory");
        }
    }
#pragma unroll
    for (int m = 1; m <= 8; m <<= 1) {
#pragma unroll
        for (int r = 0; r < 4; ++r) {
            pl0[r] += __shfl_xor(pl0[r], m);
            pl1[r] += __shfl_xor(pl1[r], m);
        }
    }
    if (lo == 0) {
        float b2v = b2[0];
#pragma unroll
        for (int r = 0; r < 4; ++r) {
            int m0 = grp * 4 + r;
            gate[pbase + m0]      = 1.f / (1.f + __expf(-(pl0[r] + b2v)));
            gate[pbase + 16 + m0] = 1.f / (1.f + __expf(-(pl1[r] + b2v)));
        }
    }
}

// ---------------------------------------------------------------------------
// Cross-attention, fp32 VALU. Grid = (b,h,t-quarter) = 384 blocks.
// ---------------------------------------------------------------------------
__global__ __launch_bounds__(256) void attn_kernel(
    const float* __restrict__ q, const float* __restrict__ k,
    const float* __restrict__ v, const float* __restrict__ gate,
    float* __restrict__ out)
{
    __shared__ float k_s[ILEN * 65];
    __shared__ float p_s[4][200];
    int bx = blockIdx.x;
    int tq = bx & 3;
    int h = (bx >> 2) % NHEADS;
    int b = bx / (4 * NHEADS);
    int tid = threadIdx.x;
    for (int idx = tid; idx < ILEN * DHEAD; idx += 256) {
        int i = idx >> 6, d = idx & 63;
        k_s[i * 65 + d] = k[(size_t)(b * ILEN + i) * HD + h * DHEAD + d];
    }
    __syncthreads();

    int l = tid & 63, w = tid >> 6;
    for (int tt = 0; tt < 4; ++tt) {
        int t = tq * 16 + w * 4 + tt;
        float qv = q[(size_t)(b * 64 + t) * HD + h * DHEAD + l];
        float s0 = 0.f, s1 = 0.f, s2 = 0.f, s3 = 0.f;
        int i0 = l, i1 = 64 + l, i2 = 128 + l;
        int i3c = (192 + l < ILEN) ? 192 + l : 0;
        for (int d = 0; d < 64; ++d) {
            float qd = __shfl(qv, d);
            s0 += qd * k_s[i0 * 65 + d];
            s1 += qd * k_s[i1 * 65 + d];
            s2 += qd * k_s[i2 * 65 + d];
            s3 += qd * k_s[i3c * 65 + d];
        }
        float sc[4] = {s0, s1, s2, s3};
        float m = -3.0e38f;
#pragma unroll
        for (int rep = 0; rep < 4; ++rep) {
            int i = rep * 64 + l;
            sc[rep] = (i < ILEN) ? sc[rep] * 0.125f : -3.0e38f;
            m = fmaxf(m, sc[rep]);
        }
        for (int mask = 32; mask >= 1; mask >>= 1) m = fmaxf(m, __shfl_xor(m, mask));
        float sum = 0.f;
#pragma unroll
        for (int rep = 0; rep < 4; ++rep) {
            float e = __expf(sc[rep] - m);
            sc[rep] = e;
            sum += e;
        }
        for (int mask = 32; mask >= 1; mask >>= 1) sum += __shfl_xor(sum, mask);
        float inv = 1.f / sum;
        const float* grow = gate + (size_t)(b * 64 + t) * ILEN;
#pragma unroll
        for (int rep = 0; rep < 4; ++rep) {
            int i = rep * 64 + l;
            if (i < 200) p_s[w][i] = (i < ILEN) ? sc[rep] * inv * grow[i] : 0.f;
        }
        float ctx = 0.f;
        const float* vbase = v + (size_t)(b * ILEN) * HD + h * DHEAD + l;
        for (int c = 0; c < 49; ++c) {
            float4 p4 = *(const float4*)&p_s[w][c * 4];
            ctx += p4.x * vbase[(size_t)(c * 4 + 0) * HD];
            ctx += p4.y * vbase[(size_t)(c * 4 + 1) * HD];
            ctx += p4.z * vbase[(size_t)(c * 4 + 2) * HD];
            ctx += p4.w * vbase[(size_t)(c * 4 + 3) * HD];
        }
        {
            float4 p4 = *(const float4*)&p_s[w][196];
            ctx += p4.x * vbase[(size_t)196 * HD];
        }
        out[(size_t)(b * 64 + t) * HD + h * DHEAD + l] = ctx;
    }
}

// ---------------------------------------------------------------------------
extern "C" void kernel_launch(void* const* d_in, const int* in_sizes, int n_in,
                              void* d_out, int out_size, void* d_ws, size_t ws_size,
                              hipStream_t stream)
{
    const float* text  = (const float*)d_in[0];
    const float* image = (const float*)d_in[1];
    const float* Wq = (const float*)d_in[2];
    const float* bq = (const float*)d_in[3];
    const float* Wk = (const float*)d_in[4];
    const float* bk = (const float*)d_in[5];
    const float* Wv = (const float*)d_in[6];
    const float* bv = (const float*)d_in[7];
    const float* Wt = (const float*)d_in[8];
    const float* bt = (const float*)d_in[9];
    const float* Wi = (const float*)d_in[10];
    const float* bi = (const float*)d_in[11];
    const float* W1 = (const float*)d_in[12];
    const float* b1 = (const float*)d_in[13];
    const float* W2 = (const float*)d_in[14];
    const float* b2 = (const float*)d_in[15];
    float* out = (float*)d_out;

    char* ws = (char*)d_ws;
    size_t off = 0;
    auto carve = [&](size_t bytes) -> void* {
        void* p = (void*)(ws + off);
        off += (bytes + 255) & ~(size_t)255;
        return p;
    };
    short* W5s  = (short*)carve((size_t)5 * 144 * 8192 * 2);   // 11.8 MB
    short* W1Ts = (short*)carve((size_t)72 * 8192 * 2);        // 1.18 MB
    float* te    = (float*)carve((size_t)512 * 768 * 4);
    float* qb    = (float*)carve((size_t)512 * 768 * 4);
    float* ieb   = (float*)carve((size_t)1576 * 768 * 4);
    float* kb    = (float*)carve((size_t)1576 * 768 * 4);
    float* vb    = (float*)carve((size_t)1576 * 768 * 4);
    float* gateb = (float*)carve((size_t)BATCH * TLEN * ILEN * 4);

    hipLaunchKernelGGL(prep_weights, dim3(864), dim3(256), 0, stream,
                       Wq, Wk, Wv, Wt, Wi, W1, W5s, W1Ts);
    hipLaunchKernelGGL(proj_kernel, dim3(8, 24), dim3(256), 0, stream,
                       text, 512, W5s, 0, bt, bq, (const float*)nullptr,
                       te, qb, (float*)nullptr);
    hipLaunchKernelGGL(proj_kernel, dim3(25, 36), dim3(256), 0, stream,
                       image, 1576, W5s, 2, bi, bk, bv,
                       ieb, kb, vb);
    hipLaunchKernelGGL(gate_kernel, dim3(788), dim3(256), 0, stream,
                       te, ieb, W1Ts, b1, W2, b2, gateb);
    hipLaunchKernelGGL(attn_kernel, dim3(BATCH * NHEADS * 4), dim3(256), 0, stream,
                       qb, kb, vb, gateb, out);
}

// Round 3
// 425.306 us; speedup vs baseline: 3.6424x; 1.1997x over previous
//
#include <hip/hip_runtime.h>
#include <stdint.h>

#define HD 768
#define NHEADS 12
#define DHEAD 64
#define BATCH 8
#define TLEN 64
#define ILEN 197

typedef __attribute__((ext_vector_type(8))) short short8;
typedef __attribute__((ext_vector_type(4))) float f32x4;

__device__ __forceinline__ short f2bf(float x) {
    union { float f; uint32_t u; } v; v.f = x;
    uint32_t r = v.u + 0x7FFFu + ((v.u >> 16) & 1u);
    return (short)(r >> 16);
}
__device__ __forceinline__ float bf2f(short s) {
    union { uint32_t u; float f; } v; v.u = ((uint32_t)(unsigned short)s) << 16;
    return v.f;
}
__device__ __forceinline__ void gll16(const void* g, void* l) {
    __builtin_amdgcn_global_load_lds(
        (const __attribute__((address_space(1))) unsigned int*)g,
        (__attribute__((address_space(3))) unsigned int*)l, 16, 0, 0);
}

// ---------------------------------------------------------------------------
// Prep: LDS-tiled transpose of weights into swizzled bf16 chunk layouts.
// W5s: 5 mats (Wt,Wq,Wi,Wk,Wv), chunks of [64 col][64 k], planes h+l:
//   short idx within plane = (col*64 + kloc) ^ ((col&7)<<3)
//   chunk base (shorts) = ((seg*12 + ntile)*12 + kt)*8192, plane l at +4096
// W1Ts: chunks [64 col][128 k], h only:
//   chunk c = ntile*6 + kt/2; idx = (col*128 + klocal) ^ ((col&7)<<3)
// Linear global_load_lds of a chunk then reproduces the swizzled LDS image.
// ---------------------------------------------------------------------------
__global__ __launch_bounds__(256) void prep_weights(
    const float* __restrict__ Wq, const float* __restrict__ Wk,
    const float* __restrict__ Wv, const float* __restrict__ Wt,
    const float* __restrict__ Wi, const float* __restrict__ W1,
    short* __restrict__ W5s, short* __restrict__ W1Ts)
{
    __shared__ float tile[64][65];
    int bx = blockIdx.x;
    int tid = threadIdx.x;
    bool isW1 = bx >= 720;
    const float* src;
    int seg, ti;
    if (isW1) { src = W1; ti = bx - 720; seg = 5; }
    else {
        seg = bx / 144; ti = bx - seg * 144;
        src = (seg == 0) ? Wt : (seg == 1) ? Wq : (seg == 2) ? Wi : (seg == 3) ? Wk : Wv;
    }
    int kt = ti / 12, ntile = ti - kt * 12;
#pragma unroll
    for (int pass = 0; pass < 16; ++pass) {
        int idx = pass * 256 + tid;
        int kk = idx >> 6, nn = idx & 63;
        tile[kk][nn] = src[(size_t)(kt * 64 + kk) * HD + ntile * 64 + nn];
    }
    __syncthreads();
    if (!isW1) {
        size_t base = ((size_t)(seg * 12 + ntile) * 12 + kt) * 8192;
#pragma unroll
        for (int pass = 0; pass < 16; ++pass) {
            int idx = pass * 256 + tid;
            int col = idx >> 6, kloc = idx & 63;
            float x = tile[kloc][col];
            short h = f2bf(x);
            short lw = f2bf(x - bf2f(h));
            int sidx = (col * 64 + kloc) ^ ((col & 7) << 3);
            W5s[base + sidx] = h;
            W5s[base + 4096 + sidx] = lw;
        }
    } else {
        int c = ntile * 6 + (kt >> 1);
        size_t base = (size_t)c * 8192;
        int khalf = (kt & 1) * 64;
#pragma unroll
        for (int pass = 0; pass < 16; ++pass) {
            int idx = pass * 256 + tid;
            int col = idx >> 6, kloc = idx & 63;
            float x = tile[kloc][col];
            int klocal = khalf + kloc;
            int sidx = (col * 128 + klocal) ^ ((col & 7) << 3);
            W1Ts[base + sidx] = f2bf(x);
        }
    }
}

// ---------------------------------------------------------------------------
// Projection GEMM (hi/lo bf16 split, near-fp32). Block = 4 waves x 16 rows,
// one 64-col n-tile; K looped over 12 LDS-staged chunks (64k x {h,l}) with
// double buffer + counted vmcnt + raw barriers.
// launch_bounds(256,1): 512-reg budget so the 192-VGPR A-frags never spill.
// ---------------------------------------------------------------------------
__global__ __launch_bounds__(256, 1) void proj_kernel(
    const float* __restrict__ X, int M,
    const short* __restrict__ W5s, int segbase,
    const float* __restrict__ bias0, const float* __restrict__ bias1,
    const float* __restrict__ bias2,
    float* __restrict__ out0, float* __restrict__ out1, float* __restrict__ out2)
{
    __shared__ __align__(16) short Bs[2][8192];
    int tid = threadIdx.x;
    int l = tid & 63, w = tid >> 6;
    int lo = l & 15, grp = l >> 4;
    int y = blockIdx.y;
    int segl = y / 12, ntile = y - segl * 12;
    int seg = segbase + segl;
    const char* wsrc = (const char*)W5s + (size_t)((seg * 12 + ntile) * 12) * 16384;
    {
        const char* s = wsrc + w * 4096 + l * 16;
        char* d = (char*)&Bs[0][0] + w * 4096;
        gll16(s, d); gll16(s + 1024, d + 1024);
        gll16(s + 2048, d + 2048); gll16(s + 3072, d + 3072);
    }
    int arow = blockIdx.x * 64 + w * 16 + lo;
    bool aok = arow < M;
    const float* xrow = X + (size_t)(aok ? arow : 0) * HD;
    short8 ah[24], al[24];
#pragma unroll
    for (int kc = 0; kc < 24; ++kc) {
        int kb = kc * 32 + grp * 8;
        float4 xa = {0.f, 0.f, 0.f, 0.f}, xb = {0.f, 0.f, 0.f, 0.f};
        if (aok) { xa = *(const float4*)(xrow + kb); xb = *(const float4*)(xrow + kb + 4); }
        float xs[8] = {xa.x, xa.y, xa.z, xa.w, xb.x, xb.y, xb.z, xb.w};
#pragma unroll
        for (int e = 0; e < 8; ++e) {
            short hh = f2bf(xs[e]);
            ah[kc][e] = hh;
            al[kc][e] = f2bf(xs[e] - bf2f(hh));
        }
    }
    __syncthreads();   // buf0 staged (drained) + all waves ready

    f32x4 acc[4];
    f32x4 z4 = {0.f, 0.f, 0.f, 0.f};
#pragma unroll
    for (int js = 0; js < 4; ++js) acc[js] = z4;

#pragma unroll
    for (int kk = 0; kk < 12; ++kk) {
        const short* buf = &Bs[kk & 1][0];
        if (kk < 11) {
            const char* s = wsrc + (size_t)(kk + 1) * 16384 + w * 4096 + l * 16;
            char* d = (char*)&Bs[(kk + 1) & 1][0] + w * 4096;
            gll16(s, d); gll16(s + 1024, d + 1024);
            gll16(s + 2048, d + 2048); gll16(s + 3072, d + 3072);
            asm volatile("s_waitcnt vmcnt(4)" ::: "memory");
        } else {
            asm volatile("s_waitcnt vmcnt(0)" ::: "memory");
        }
        __builtin_amdgcn_s_barrier();
        asm volatile("" ::: "memory");
#pragma unroll
        for (int js = 0; js < 4; ++js) {
            int col = js * 16 + lo;
            int base = col * 64;
            int sw = (col & 7) << 3;
#pragma unroll
            for (int kcl = 0; kcl < 2; ++kcl) {
                int idx = (base + kcl * 32 + grp * 8) ^ sw;
                short8 bh = *(const short8*)&buf[idx];
                short8 bl = *(const short8*)&buf[4096 + idx];
                int kc = kk * 2 + kcl;
                acc[js] = __builtin_amdgcn_mfma_f32_16x16x32_bf16(ah[kc], bh, acc[js], 0, 0, 0);
                acc[js] = __builtin_amdgcn_mfma_f32_16x16x32_bf16(ah[kc], bl, acc[js], 0, 0, 0);
                acc[js] = __builtin_amdgcn_mfma_f32_16x16x32_bf16(al[kc], bh, acc[js], 0, 0, 0);
            }
        }
        asm volatile("s_waitcnt lgkmcnt(0)" ::: "memory");
        __builtin_amdgcn_s_barrier();
        asm volatile("" ::: "memory");
    }
    const float* bp = (segl == 0) ? bias0 : (segl == 1) ? bias1 : bias2;
    float* op = (segl == 0) ? out0 : (segl == 1) ? out1 : out2;
#pragma unroll
    for (int js = 0; js < 4; ++js) {
        int cc = ntile * 64 + js * 16 + lo;
        float bvv = bp[cc];
#pragma unroll
        for (int r = 0; r < 4; ++r) {
            int orow = blockIdx.x * 64 + w * 16 + grp * 4 + r;
            if (orow < M) op[(size_t)orow * HD + cc] = acc[js][r] + bvv;
        }
    }
}

// ---------------------------------------------------------------------------
// Gate MLP: flattened pairs p = ((b*64+t)*197+i), 788 blocks x 128 rows
// (4 waves x 32 rows: 2 A-frags, full K=768 in 192 VGPRs). Loops 12 n-tiles
// x 6 K-chunks (64col x 128k, 16 KB) LDS double-buffered; epilogue fuses
// relu + W2 reduction; writes sigmoid(logit). No atomics, zero padding waste.
// launch_bounds(256,1): 512-reg budget -> A-frags live in arch VGPRs, acc in
// AGPRs, no scratch spill (R2's (256,2) split 128 arch + 128 acc -> 490 MB of
// scratch traffic).
// ---------------------------------------------------------------------------
__global__ __launch_bounds__(256, 1) void gate_kernel(
    const float* __restrict__ te, const float* __restrict__ ie,
    const short* __restrict__ W1Ts, const float* __restrict__ b1,
    const float* __restrict__ W2, const float* __restrict__ b2,
    float* __restrict__ gate)
{
    __shared__ __align__(16) short Bs[2][8192];
    __shared__ float bw_s[1536];
    int tid = threadIdx.x;
    int l = tid & 63, w = tid >> 6;
    int lo = l & 15, grp = l >> 4;
    int pbase = blockIdx.x * 128 + w * 32;

    const char* wsrc = (const char*)W1Ts;
    {
        const char* s = wsrc + w * 4096 + l * 16;
        char* d = (char*)&Bs[0][0] + w * 4096;
        gll16(s, d); gll16(s + 1024, d + 1024);
        gll16(s + 2048, d + 2048); gll16(s + 3072, d + 3072);
    }
    for (int idx = tid; idx < 1536; idx += 256)
        bw_s[idx] = (idx < 768) ? b1[idx] : W2[idx - 768];

    short8 a0[24], a1[24];
    {
        int p0 = pbase + lo;
        int bb = p0 / 12608; int rr = p0 - bb * 12608;
        int t0 = rr / 197;   int i0 = rr - t0 * 197;
        const float* tp = te + (size_t)(bb * 64 + t0) * HD;
        const float* ip = ie + (size_t)(bb * 197 + i0) * HD;
#pragma unroll
        for (int kc = 0; kc < 24; ++kc) {
            int kb = kc * 32 + grp * 8;
            float4 xa = *(const float4*)(ip + kb);
            float4 xb = *(const float4*)(ip + kb + 4);
            float4 ta = *(const float4*)(tp + kb);
            float4 tb = *(const float4*)(tp + kb + 4);
            a0[kc][0] = f2bf(xa.x * ta.x); a0[kc][1] = f2bf(xa.y * ta.y);
            a0[kc][2] = f2bf(xa.z * ta.z); a0[kc][3] = f2bf(xa.w * ta.w);
            a0[kc][4] = f2bf(xb.x * tb.x); a0[kc][5] = f2bf(xb.y * tb.y);
            a0[kc][6] = f2bf(xb.z * tb.z); a0[kc][7] = f2bf(xb.w * tb.w);
        }
    }
    {
        int p1 = pbase + 16 + lo;
        int bb = p1 / 12608; int rr = p1 - bb * 12608;
        int t1 = rr / 197;   int i1 = rr - t1 * 197;
        const float* tp = te + (size_t)(bb * 64 + t1) * HD;
        const float* ip = ie + (size_t)(bb * 197 + i1) * HD;
#pragma unroll
        for (int kc = 0; kc < 24; ++kc) {
            int kb = kc * 32 + grp * 8;
            float4 xa = *(const float4*)(ip + kb);
            float4 xb = *(const float4*)(ip + kb + 4);
            float4 ta = *(const float4*)(tp + kb);
            float4 tb = *(const float4*)(tp + kb + 4);
            a1[kc][0] = f2bf(xa.x * ta.x); a1[kc][1] = f2bf(xa.y * ta.y);
            a1[kc][2] = f2bf(xa.z * ta.z); a1[kc][3] = f2bf(xa.w * ta.w);
            a1[kc][4] = f2bf(xb.x * tb.x); a1[kc][5] = f2bf(xb.y * tb.y);
            a1[kc][6] = f2bf(xb.z * tb.z); a1[kc][7] = f2bf(xb.w * tb.w);
        }
    }
    __syncthreads();   // buf0 ready, bw_s ready

    f32x4 z4 = {0.f, 0.f, 0.f, 0.f};
    f32x4 acc0[4], acc1[4];
#pragma unroll
    for (int js = 0; js < 4; ++js) { acc0[js] = z4; acc1[js] = z4; }
    float pl0[4] = {0.f, 0.f, 0.f, 0.f}, pl1[4] = {0.f, 0.f, 0.f, 0.f};

    for (int nt = 0; nt < 12; ++nt) {
#pragma unroll
        for (int kk = 0; kk < 6; ++kk) {
            int c = nt * 6 + kk;
            const short* buf = &Bs[kk & 1][0];
            if (c < 71) {
                const char* s = wsrc + (size_t)(c + 1) * 16384 + w * 4096 + l * 16;
                char* d = (char*)&Bs[(kk + 1) & 1][0] + w * 4096;
                gll16(s, d); gll16(s + 1024, d + 1024);
                gll16(s + 2048, d + 2048); gll16(s + 3072, d + 3072);
                asm volatile("s_waitcnt vmcnt(4)" ::: "memory");
            } else {
                asm volatile("s_waitcnt vmcnt(0)" ::: "memory");
            }
            __builtin_amdgcn_s_barrier();
            asm volatile("" ::: "memory");
#pragma unroll
            for (int js = 0; js < 4; ++js) {
                int col = js * 16 + lo;
                int base = col * 128;
                int sw = (col & 7) << 3;
#pragma unroll
                for (int kcl = 0; kcl < 4; ++kcl) {
                    int idx = (base + kcl * 32 + grp * 8) ^ sw;
                    short8 bf = *(const short8*)&buf[idx];
                    acc0[js] = __builtin_amdgcn_mfma_f32_16x16x32_bf16(a0[kk * 4 + kcl], bf, acc0[js], 0, 0, 0);
                    acc1[js] = __builtin_amdgcn_mfma_f32_16x16x32_bf16(a1[kk * 4 + kcl], bf, acc1[js], 0, 0, 0);
                }
            }
            if (kk == 5) {
#pragma unroll
                for (int js = 0; js < 4; ++js) {
                    int j = nt * 64 + js * 16 + lo;
                    float b1v = bw_s[j], w2v = bw_s[768 + j];
#pragma unroll
                    for (int r = 0; r < 4; ++r) {
                        pl0[r] += fmaxf(acc0[js][r] + b1v, 0.f) * w2v;
                        pl1[r] += fmaxf(acc1[js][r] + b1v, 0.f) * w2v;
                    }
                    acc0[js] = z4; acc1[js] = z4;
                }
            }
            asm volatile("s_waitcnt lgkmcnt(0)" ::: "memory");
            __builtin_amdgcn_s_barrier();
            asm volatile("" ::: "memory");
        }
    }
#pragma unroll
    for (int m = 1; m <= 8; m <<= 1) {
#pragma unroll
        for (int r = 0; r < 4; ++r) {
            pl0[r] += __shfl_xor(pl0[r], m);
            pl1[r] += __shfl_xor(pl1[r], m);
        }
    }
    if (lo == 0) {
        float b2v = b2[0];
#pragma unroll
        for (int r = 0; r < 4; ++r) {
            int m0 = grp * 4 + r;
            gate[pbase + m0]      = 1.f / (1.f + __expf(-(pl0[r] + b2v)));
            gate[pbase + 16 + m0] = 1.f / (1.f + __expf(-(pl1[r] + b2v)));
        }
    }
}

// ---------------------------------------------------------------------------
// Cross-attention, fp32 VALU. Grid = (b,h,t-quarter) = 384 blocks.
// ---------------------------------------------------------------------------
__global__ __launch_bounds__(256) void attn_kernel(
    const float* __restrict__ q, const float* __restrict__ k,
    const float* __restrict__ v, const float* __restrict__ gate,
    float* __restrict__ out)
{
    __shared__ float k_s[ILEN * 65];
    __shared__ float p_s[4][200];
    int bx = blockIdx.x;
    int tq = bx & 3;
    int h = (bx >> 2) % NHEADS;
    int b = bx / (4 * NHEADS);
    int tid = threadIdx.x;
    for (int idx = tid; idx < ILEN * DHEAD; idx += 256) {
        int i = idx >> 6, d = idx & 63;
        k_s[i * 65 + d] = k[(size_t)(b * ILEN + i) * HD + h * DHEAD + d];
    }
    __syncthreads();

    int l = tid & 63, w = tid >> 6;
    for (int tt = 0; tt < 4; ++tt) {
        int t = tq * 16 + w * 4 + tt;
        float qv = q[(size_t)(b * 64 + t) * HD + h * DHEAD + l];
        float s0 = 0.f, s1 = 0.f, s2 = 0.f, s3 = 0.f;
        int i0 = l, i1 = 64 + l, i2 = 128 + l;
        int i3c = (192 + l < ILEN) ? 192 + l : 0;
        for (int d = 0; d < 64; ++d) {
            float qd = __shfl(qv, d);
            s0 += qd * k_s[i0 * 65 + d];
            s1 += qd * k_s[i1 * 65 + d];
            s2 += qd * k_s[i2 * 65 + d];
            s3 += qd * k_s[i3c * 65 + d];
        }
        float sc[4] = {s0, s1, s2, s3};
        float m = -3.0e38f;
#pragma unroll
        for (int rep = 0; rep < 4; ++rep) {
            int i = rep * 64 + l;
            sc[rep] = (i < ILEN) ? sc[rep] * 0.125f : -3.0e38f;
            m = fmaxf(m, sc[rep]);
        }
        for (int mask = 32; mask >= 1; mask >>= 1) m = fmaxf(m, __shfl_xor(m, mask));
        float sum = 0.f;
#pragma unroll
        for (int rep = 0; rep < 4; ++rep) {
            float e = __expf(sc[rep] - m);
            sc[rep] = e;
            sum += e;
        }
        for (int mask = 32; mask >= 1; mask >>= 1) sum += __shfl_xor(sum, mask);
        float inv = 1.f / sum;
        const float* grow = gate + (size_t)(b * 64 + t) * ILEN;
#pragma unroll
        for (int rep = 0; rep < 4; ++rep) {
            int i = rep * 64 + l;
            if (i < 200) p_s[w][i] = (i < ILEN) ? sc[rep] * inv * grow[i] : 0.f;
        }
        float ctx = 0.f;
        const float* vbase = v + (size_t)(b * ILEN) * HD + h * DHEAD + l;
        for (int c = 0; c < 49; ++c) {
            float4 p4 = *(const float4*)&p_s[w][c * 4];
            ctx += p4.x * vbase[(size_t)(c * 4 + 0) * HD];
            ctx += p4.y * vbase[(size_t)(c * 4 + 1) * HD];
            ctx += p4.z * vbase[(size_t)(c * 4 + 2) * HD];
            ctx += p4.w * vbase[(size_t)(c * 4 + 3) * HD];
        }
        {
            float4 p4 = *(const float4*)&p_s[w][196];
            ctx += p4.x * vbase[(size_t)196 * HD];
        }
        out[(size_t)(b * 64 + t) * HD + h * DHEAD + l] = ctx;
    }
}

// ---------------------------------------------------------------------------
extern "C" void kernel_launch(void* const* d_in, const int* in_sizes, int n_in,
                              void* d_out, int out_size, void* d_ws, size_t ws_size,
                              hipStream_t stream)
{
    const float* text  = (const float*)d_in[0];
    const float* image = (const float*)d_in[1];
    const float* Wq = (const float*)d_in[2];
    const float* bq = (const float*)d_in[3];
    const float* Wk = (const float*)d_in[4];
    const float* bk = (const float*)d_in[5];
    const float* Wv = (const float*)d_in[6];
    const float* bv = (const float*)d_in[7];
    const float* Wt = (const float*)d_in[8];
    const float* bt = (const float*)d_in[9];
    const float* Wi = (const float*)d_in[10];
    const float* bi = (const float*)d_in[11];
    const float* W1 = (const float*)d_in[12];
    const float* b1 = (const float*)d_in[13];
    const float* W2 = (const float*)d_in[14];
    const float* b2 = (const float*)d_in[15];
    float* out = (float*)d_out;

    char* ws = (char*)d_ws;
    size_t off = 0;
    auto carve = [&](size_t bytes) -> void* {
        void* p = (void*)(ws + off);
        off += (bytes + 255) & ~(size_t)255;
        return p;
    };
    short* W5s  = (short*)carve((size_t)5 * 144 * 8192 * 2);   // 11.8 MB
    short* W1Ts = (short*)carve((size_t)72 * 8192 * 2);        // 1.18 MB
    float* te    = (float*)carve((size_t)512 * 768 * 4);
    float* qb    = (float*)carve((size_t)512 * 768 * 4);
    float* ieb   = (float*)carve((size_t)1576 * 768 * 4);
    float* kb    = (float*)carve((size_t)1576 * 768 * 4);
    float* vb    = (float*)carve((size_t)1576 * 768 * 4);
    float* gateb = (float*)carve((size_t)BATCH * TLEN * ILEN * 4);

    hipLaunchKernelGGL(prep_weights, dim3(864), dim3(256), 0, stream,
                       Wq, Wk, Wv, Wt, Wi, W1, W5s, W1Ts);
    hipLaunchKernelGGL(proj_kernel, dim3(8, 24), dim3(256), 0, stream,
                       text, 512, W5s, 0, bt, bq, (const float*)nullptr,
                       te, qb, (float*)nullptr);
    hipLaunchKernelGGL(proj_kernel, dim3(25, 36), dim3(256), 0, stream,
                       image, 1576, W5s, 2, bi, bk, bv,
                       ieb, kb, vb);
    hipLaunchKernelGGL(gate_kernel, dim3(788), dim3(256), 0, stream,
                       te, ieb, W1Ts, b1, W2, b2, gateb);
    hipLaunchKernelGGL(attn_kernel, dim3(BATCH * NHEADS * 4), dim3(256), 0, stream,
                       qb, kb, vb, gateb, out);
}